// Round 5
// baseline (42.588 us; speedup 1.0000x reference)
//
#include <hip/hip_runtime.h>
#include <math.h>

#define CH_EPS 1e-6f
#define CH_N   4096
#define CH_BS  8
#define CH_JC  32                  // j-chunks
#define CH_JCH (CH_N / CH_JC)      // 128 points per chunk
#define CH_TI  4                   // own points per thread
// block = 256 threads, TI=4 -> 1024 i per block, 4 i-tiles
// blocks = 4 * 32 * 8 * 2 = 2048 -> 8 waves/SIMD

// part[dir][b][jc][i] : 2*8*32*4096 floats = 8 MB in d_ws
#define PART_IDX(dir, b, jc, i) \
    ((((size_t)(dir) * CH_BS + (b)) * CH_JC + (jc)) * CH_N + (i))

// ---------------- scan: per (i-tile, j-chunk) partial min ----------------
// dir 0: own=y, other=x ; dir 1: own=x, other=y
// d2 = p2 + (q2 - 2 p.q); track min_j (q2 - 2 p.q), add p2 at the end.
__global__ __launch_bounds__(256, 8) void chamfer_scan_kernel(
    const float* __restrict__ x, const float* __restrict__ y,
    float* __restrict__ part, float* __restrict__ out) {
    const int tid = threadIdx.x;
    const int it  = blockIdx.x >> 5;    // i-tile [0,4)
    const int jc  = blockIdx.x & 31;    // j-chunk [0,32)
    const int b   = blockIdx.y;
    const int dir = blockIdx.z;

    // zero the output once per call (finalize dispatch runs after us)
    if (blockIdx.x == 0 && b == 0 && dir == 0 && tid < CH_BS) out[tid] = 0.0f;

    const float* own   = dir ? x : y;
    const float* other = dir ? y : x;

    // ---- stage j-chunk into LDS as {q, |q|^2} ----
    __shared__ float4 q4s[CH_JCH];   // 2 KB
    if (tid < CH_JCH) {
        const float* qsrc = other + ((size_t)b * CH_N + (size_t)jc * CH_JCH + tid) * 3;
        const float a = qsrc[0], c = qsrc[1], e = qsrc[2];
        q4s[tid] = make_float4(a, c, e, a * a + c * c + e * e);
    }
    __syncthreads();

    // ---- own points: i0 + {0,256,512,768} ----
    const int i0 = it * 1024 + tid;
    float nx[CH_TI], ny[CH_TI], nz[CH_TI], p2[CH_TI];
#pragma unroll
    for (int t = 0; t < CH_TI; ++t) {
        const float* op = own + ((size_t)b * CH_N + i0 + t * 256) * 3;
        const float px = op[0], py = op[1], pz = op[2];
        p2[t] = px * px + py * py + pz * pz;
        nx[t] = -2.0f * px; ny[t] = -2.0f * py; nz[t] = -2.0f * pz;
    }

    float m0[CH_TI], m1[CH_TI];
#pragma unroll
    for (int t = 0; t < CH_TI; ++t) { m0[t] = 3.4e38f; m1[t] = 3.4e38f; }

    // ---- inner scan: 4 broadcast ds_read_b128 feed 16 pair-evals ----
    for (int j0 = 0; j0 < CH_JCH; j0 += 4) {
        float4 qv[4];
#pragma unroll
        for (int k = 0; k < 4; ++k) qv[k] = q4s[j0 + k];
#pragma unroll
        for (int t = 0; t < CH_TI; ++t) {
            const float t0 = fmaf(nx[t], qv[0].x, fmaf(ny[t], qv[0].y, fmaf(nz[t], qv[0].z, qv[0].w)));
            const float t1 = fmaf(nx[t], qv[1].x, fmaf(ny[t], qv[1].y, fmaf(nz[t], qv[1].z, qv[1].w)));
            const float t2 = fmaf(nx[t], qv[2].x, fmaf(ny[t], qv[2].y, fmaf(nz[t], qv[2].z, qv[2].w)));
            const float t3 = fmaf(nx[t], qv[3].x, fmaf(ny[t], qv[3].y, fmaf(nz[t], qv[3].z, qv[3].w)));
            // fminf chains -> v_min3_f32
            m0[t] = fminf(fminf(m0[t], t0), t2);
            m1[t] = fminf(fminf(m1[t], t1), t3);
        }
    }

#pragma unroll
    for (int t = 0; t < CH_TI; ++t) {
        const float r = fminf(m0[t], m1[t]) + p2[t];
        part[PART_IDX(dir, b, jc, i0 + t * 256)] = r;
    }
}

// ---------------- finalize: min over chunks, sqrt, mean, accumulate ----------------
// grid (CH_BS, 16 slices of 256 i); out zeroed by the scan dispatch.
__global__ __launch_bounds__(256) void chamfer_finalize_kernel(
    const float* __restrict__ part, float* __restrict__ out) {
    const int b   = blockIdx.x;
    const int sl  = blockIdx.y;
    const int tid = threadIdx.x;
    const int i   = sl * 256 + tid;

    float s = 0.0f;
#pragma unroll
    for (int dir = 0; dir < 2; ++dir) {
        const size_t base = PART_IDX(dir, b, 0, i);
        float m = part[base];
#pragma unroll 8
        for (int jc = 1; jc < CH_JC; ++jc)
            m = fminf(m, part[base + (size_t)jc * CH_N]);
        s += sqrtf(CH_EPS + fmaxf(m, 0.0f));
    }
    s *= (1.0f / (float)CH_N);

#pragma unroll
    for (int off = 32; off > 0; off >>= 1) s += __shfl_down(s, off, 64);

    __shared__ float wsum[4];
    if ((tid & 63) == 0) wsum[tid >> 6] = s;
    __syncthreads();
    if (tid == 0) atomicAdd(out + b, wsum[0] + wsum[1] + wsum[2] + wsum[3]);
}

extern "C" void kernel_launch(void* const* d_in, const int* in_sizes, int n_in,
                              void* d_out, int out_size, void* d_ws, size_t ws_size,
                              hipStream_t stream) {
    const float* x = (const float*)d_in[0];
    const float* y = (const float*)d_in[1];
    float* out  = (float*)d_out;
    float* part = (float*)d_ws;

    // scan: 4 i-tiles x 32 j-chunks, 8 batches, 2 dirs = 2048 blocks
    chamfer_scan_kernel<<<dim3(4 * CH_JC, CH_BS, 2), dim3(256), 0, stream>>>(x, y, part, out);

    // finalize: 128 blocks
    chamfer_finalize_kernel<<<dim3(CH_BS, 16), dim3(256), 0, stream>>>(part, out);
}

// Round 6
// 30.985 us; speedup vs baseline: 1.3744x; 1.3744x over previous
//
#include <hip/hip_runtime.h>
#include <math.h>

#define CH_EPS 1e-6f
#define CH_N   4096
#define CH_BS  8
#define CH_JC  16                  // j-chunks
#define CH_JCH (CH_N / CH_JC)      // 256 points per chunk
#define CH_TI  2                   // own points per thread
// block = 256 threads, TI=2 -> 512 i per block, 8 i-tiles
// blocks = 8 * 16 * 8 * 2 = 2048 -> 8 waves/SIMD

// part[dir][b][jc][i] : 2*8*16*4096 floats = 4 MB in d_ws
#define PART_IDX(dir, b, jc, i) \
    ((((size_t)(dir) * CH_BS + (b)) * CH_JC + (jc)) * CH_N + (i))

// ---------------- scan: per (i-tile, j-chunk) partial min ----------------
// dir 0: own=y, other=x ; dir 1: own=x, other=y
// d2 = p2 + (q2 - 2 p.q); track min_j (q2 - 2 p.q), add p2 at the end.
__global__ __launch_bounds__(256) void chamfer_scan_kernel(
    const float* __restrict__ x, const float* __restrict__ y,
    float* __restrict__ part, float* __restrict__ out) {
    const int tid = threadIdx.x;
    const int it  = blockIdx.x >> 4;    // i-tile [0,8)
    const int jc  = blockIdx.x & 15;    // j-chunk [0,16)
    const int b   = blockIdx.y;
    const int dir = blockIdx.z;

    // zero the output once per call (finalize dispatch runs after us)
    if (blockIdx.x == 0 && b == 0 && dir == 0 && tid < CH_BS) out[tid] = 0.0f;

    const float* own   = dir ? x : y;
    const float* other = dir ? y : x;

    // ---- stage j-chunk into LDS as {q, |q|^2}: one point per thread ----
    __shared__ float4 q4s[CH_JCH];   // 4 KB
    {
        const float* qsrc = other + ((size_t)b * CH_N + (size_t)jc * CH_JCH + tid) * 3;
        const float a = qsrc[0], c = qsrc[1], e = qsrc[2];
        q4s[tid] = make_float4(a, c, e, a * a + c * c + e * e);
    }
    __syncthreads();

    // ---- own points: i0 and i0+256 ----
    const int i0 = it * 512 + tid;
    const int i1 = i0 + 256;
    const float* op0 = own + ((size_t)b * CH_N + i0) * 3;
    const float* op1 = own + ((size_t)b * CH_N + i1) * 3;
    const float px0 = op0[0], py0 = op0[1], pz0 = op0[2];
    const float px1 = op1[0], py1 = op1[1], pz1 = op1[2];
    const float p20 = px0 * px0 + py0 * py0 + pz0 * pz0;
    const float p21 = px1 * px1 + py1 * py1 + pz1 * pz1;
    const float nx0 = -2.0f * px0, ny0 = -2.0f * py0, nz0 = -2.0f * pz0;
    const float nx1 = -2.0f * px1, ny1 = -2.0f * py1, nz1 = -2.0f * pz1;

    float m0[2], m1[2];
    m0[0] = m0[1] = m1[0] = m1[1] = 3.4e38f;

    // ---- inner scan: 4 broadcast ds_read_b128 + 24 fma + 4 min3 per step ----
    for (int j0 = 0; j0 < CH_JCH; j0 += 4) {
        float4 qv[4];
#pragma unroll
        for (int k = 0; k < 4; ++k) qv[k] = q4s[j0 + k];

        const float e00 = fmaf(nx0, qv[0].x, fmaf(ny0, qv[0].y, fmaf(nz0, qv[0].z, qv[0].w)));
        const float e01 = fmaf(nx0, qv[1].x, fmaf(ny0, qv[1].y, fmaf(nz0, qv[1].z, qv[1].w)));
        const float e02 = fmaf(nx0, qv[2].x, fmaf(ny0, qv[2].y, fmaf(nz0, qv[2].z, qv[2].w)));
        const float e03 = fmaf(nx0, qv[3].x, fmaf(ny0, qv[3].y, fmaf(nz0, qv[3].z, qv[3].w)));
        const float e10 = fmaf(nx1, qv[0].x, fmaf(ny1, qv[0].y, fmaf(nz1, qv[0].z, qv[0].w)));
        const float e11 = fmaf(nx1, qv[1].x, fmaf(ny1, qv[1].y, fmaf(nz1, qv[1].z, qv[1].w)));
        const float e12 = fmaf(nx1, qv[2].x, fmaf(ny1, qv[2].y, fmaf(nz1, qv[2].z, qv[2].w)));
        const float e13 = fmaf(nx1, qv[3].x, fmaf(ny1, qv[3].y, fmaf(nz1, qv[3].z, qv[3].w)));

        // fminf(fminf(a,b),c) -> v_min3_f32
        m0[0] = fminf(fminf(m0[0], e00), e01);
        m0[1] = fminf(fminf(m0[1], e02), e03);
        m1[0] = fminf(fminf(m1[0], e10), e11);
        m1[1] = fminf(fminf(m1[1], e12), e13);
    }

    part[PART_IDX(dir, b, jc, i0)] = fminf(m0[0], m0[1]) + p20;
    part[PART_IDX(dir, b, jc, i1)] = fminf(m1[0], m1[1]) + p21;
}

// ---------------- finalize: min over chunks, sqrt, mean, accumulate ----------------
// grid (CH_BS, 16 slices of 256 i); out zeroed by the scan dispatch.
__global__ __launch_bounds__(256) void chamfer_finalize_kernel(
    const float* __restrict__ part, float* __restrict__ out) {
    const int b   = blockIdx.x;
    const int sl  = blockIdx.y;
    const int tid = threadIdx.x;
    const int i   = sl * 256 + tid;

    float s = 0.0f;
#pragma unroll
    for (int dir = 0; dir < 2; ++dir) {
        const size_t base = PART_IDX(dir, b, 0, i);
        float m = part[base];
#pragma unroll
        for (int jc = 1; jc < CH_JC; ++jc)
            m = fminf(m, part[base + (size_t)jc * CH_N]);
        s += sqrtf(CH_EPS + fmaxf(m, 0.0f));
    }
    s *= (1.0f / (float)CH_N);

#pragma unroll
    for (int off = 32; off > 0; off >>= 1) s += __shfl_down(s, off, 64);

    __shared__ float wsum[4];
    if ((tid & 63) == 0) wsum[tid >> 6] = s;
    __syncthreads();
    if (tid == 0) atomicAdd(out + b, wsum[0] + wsum[1] + wsum[2] + wsum[3]);
}

extern "C" void kernel_launch(void* const* d_in, const int* in_sizes, int n_in,
                              void* d_out, int out_size, void* d_ws, size_t ws_size,
                              hipStream_t stream) {
    const float* x = (const float*)d_in[0];
    const float* y = (const float*)d_in[1];
    float* out  = (float*)d_out;
    float* part = (float*)d_ws;

    // scan: 8 i-tiles x 16 j-chunks, 8 batches, 2 dirs = 2048 blocks
    chamfer_scan_kernel<<<dim3(8 * CH_JC, CH_BS, 2), dim3(256), 0, stream>>>(x, y, part, out);

    // finalize: 128 blocks
    chamfer_finalize_kernel<<<dim3(CH_BS, 16), dim3(256), 0, stream>>>(part, out);
}